// Round 9
// baseline (270.539 us; speedup 1.0000x reference)
//
#include <hip/hip_runtime.h>

// Patch_Embed_Center_Rotate: x (256,3,224,224) f32, P=16, grid 14x14.
// out = x everywhere, except patches with grid col j in [5,9] AND grid row
// k in [5,9], which are transposed within the 16x16 patch:
//   out[b,c, k*16+a3, j*16+a4] = x[b,c, k*16+a4, j*16+a3]
//
// v9 = v8 per-element logic (plain cached loads, nt stores — best family)
// with the G11 memory-bound launch shape, the one untested lever:
//   2352 blocks x 256 thr; each block does 4 tiles of 1024 f4; per tile a
//   thread issues 4 INDEPENDENT coalesced f4 loads back-to-back (4x MLP
//   per wave vs v8's single outstanding load), fixes center elements, then
//   4 nt stores. 16x fewer block launches than v8's 37,632 one-shot blocks.
// v3's fat-block regression doesn't cover this: that had barrier-coupled
// LDS phases and 768 blocks; here iterations are independent and unrolled.
// Ledger (fill-normalized kernel us): v4.1/v8 ~60-66, v5 ~65, v7 ~72,
// v6 ~80; floor ~47. Prediction: ~50-54 -> dur ~240-247. If neutral,
// all single levers are falsified -> declare ceiling next round.

#define IMGF4 12544   // 224*56 f4 per (b,c) image
#define NBLK 2352     // 9408 tiles / 4 per block; 2352*4*1024 = 9,633,792 f4

typedef float vf4 __attribute__((ext_vector_type(4)));

__global__ __launch_bounds__(256) void patch_rotate_kernel(
    const float* __restrict__ x, float* __restrict__ out) {
  const int tid = threadIdx.x;
#pragma unroll
  for (int it = 0; it < 4; ++it) {
    const int tile = blockIdx.x + it * NBLK;       // 0..9407
    const int base = tile * 1024 + tid;
    int idx[4];
    vf4 v[4];
    // 4 independent full-line coalesced loads, issued back-to-back.
#pragma unroll
    for (int u = 0; u < 4; ++u) {
      idx[u] = base + u * 256;
      v[u] = *((const vf4*)x + idx[u]);
    }
    // predicate + center gather-overwrite (12.75% of elements; proven cheap).
#pragma unroll
    for (int u = 0; u < 4; ++u) {
      const int rem  = idx[u] % IMGF4;
      const int row  = rem / 56;                   // 0..223
      const int col4 = rem % 56;                   // 0..55
      const int k = row >> 4;
      const int j = col4 >> 2;
      if ((j >= 5) & (j <= 9) & (k >= 5) & (k <= 9)) {
        const int bc  = idx[u] / IMGF4;
        const int a3  = row & 15;
        const int a4b = (col4 & 3) << 2;
        const int sb  = (bc * 224 + (k << 4)) * 224 + (j << 4) + a3;
        v[u].x = x[sb + (a4b + 0) * 224];
        v[u].y = x[sb + (a4b + 1) * 224];
        v[u].z = x[sb + (a4b + 2) * 224];
        v[u].w = x[sb + (a4b + 3) * 224];
      }
    }
    // nt stores (no write-allocate -- the one proven win).
#pragma unroll
    for (int u = 0; u < 4; ++u)
      __builtin_nontemporal_store(v[u], (vf4*)out + idx[u]);
  }
}

extern "C" void kernel_launch(void* const* d_in, const int* in_sizes, int n_in,
                              void* d_out, int out_size, void* d_ws, size_t ws_size,
                              hipStream_t stream) {
  const float* x = (const float*)d_in[0];
  float* out = (float*)d_out;
  patch_rotate_kernel<<<NBLK, 256, 0, stream>>>(x, out);
}

// Round 10
// 252.198 us; speedup vs baseline: 1.0727x; 1.0727x over previous
//
#include <hip/hip_runtime.h>

// Patch_Embed_Center_Rotate: x (256,3,224,224) f32, P=16, grid 14x14.
// out = x everywhere, except patches with grid col j in [5,9] AND grid row
// k in [5,9], which are transposed within the 16x16 patch:
//   out[b,c, k*16+a3, j*16+a4] = x[b,c, k*16+a4, j*16+a3]
//
// v10 = v8 restored (best measured: raw dur 252.4 us). One thread per f4,
// 37,632 one-shot blocks, predicated center-gather in-pass, plain cached
// loads + nontemporal stores.
// Why this shape won (9-round evidence):
//  - nt STORES: no write-allocate; keeps out of L3 so x stays read-resident
//    (round-9 counters: FETCH 84.5 MB < 147 MB input = L3 serves ~42% of
//    reads across iterations). The only lever that moved time (~16 us).
//  - cached LOADS: preserve that L3 read-residency (nt loads ~neutral).
//  - massive one-shot grid: fat-block/MLP variants regressed twice
//    (v3 ~82 us, v9 98 us w/ 54% occupancy + 2.4 TB/s); fills prove BW
//    saturates at 9% occupancy, TLP churn is the winning latency-hider.
//  - center path in-pass: role-split (v5), LDS transpose (v2), and
//    copy+fixup (v7) all neutral-to-worse; the scattered gather is
//    latency-hidden behind the stream.
// Kernel ~60-66 us (294 MB round trip ~4.5-4.9 TB/s); measured dur floor
// ~252 us includes ~186 us of harness reset fills.

#define HH 224
#define WW 224
#define W4 56  // 224/4

typedef float vf4 __attribute__((ext_vector_type(4)));

__global__ __launch_bounds__(256) void patch_rotate_kernel(
    const float* __restrict__ x, float* __restrict__ out, int n4) {
  int idx = blockIdx.x * blockDim.x + threadIdx.x;  // float4 index into out
  if (idx >= n4) return;

  int bc   = idx / (HH * W4);   // fused (b,c)
  int rem  = idx % (HH * W4);
  int row  = rem / W4;          // 0..223
  int col4 = rem % W4;          // 0..55

  int k = row >> 4;     // grid row
  int j = col4 >> 2;    // grid col  (col4*4/16)

  bool center = (j >= 5) & (j <= 9) & (k >= 5) & (k <= 9);

  if (!center) {
    vf4 v = *((const vf4*)x + idx);
    __builtin_nontemporal_store(v, (vf4*)out + idx);
  } else {
    // transposed patch: out col a4 -> src row k*16+a4; out row a3 -> src col.
    int a3  = row & 15;
    int a4b = (col4 & 3) << 2;            // first of 4 a4 values
    int base = (bc * HH + (k << 4)) * WW + (j << 4) + a3;  // a4 = 0 element
    vf4 v;
    v.x = x[base + (a4b + 0) * WW];
    v.y = x[base + (a4b + 1) * WW];
    v.z = x[base + (a4b + 2) * WW];
    v.w = x[base + (a4b + 3) * WW];
    __builtin_nontemporal_store(v, (vf4*)out + idx);
  }
}

extern "C" void kernel_launch(void* const* d_in, const int* in_sizes, int n_in,
                              void* d_out, int out_size, void* d_ws, size_t ws_size,
                              hipStream_t stream) {
  const float* x = (const float*)d_in[0];
  float* out = (float*)d_out;
  int n4 = out_size / 4;                       // 9,633,792 float4s
  int threads = 256;
  int blocks = (n4 + threads - 1) / threads;   // 37,632
  patch_rotate_kernel<<<blocks, threads, 0, stream>>>(x, out, n4);
}